// Round 4
// baseline (169.936 us; speedup 1.0000x reference)
//
#include <hip/hip_runtime.h>

typedef short bf16x8 __attribute__((ext_vector_type(8)));
typedef float f32x16 __attribute__((ext_vector_type(16)));

#define DI __device__ __forceinline__

constexpr int BS = 2, CH = 128;
constexpr int NQ = 16384, NM = 4096;
constexpr size_t NX = (size_t)BS * CH * NQ;   // elements per output tensor

DI float bf2f(ushort u) { unsigned v = ((unsigned)u) << 16; return __builtin_bit_cast(float, v); }
DI ushort f2bf(float f) {
  unsigned u = __builtin_bit_cast(unsigned, f);
  u += 0x7FFFu + ((u >> 16) & 1u);   // RNE
  return (ushort)(u >> 16);
}
DI float ldany(const void* p, size_t i, int f) {
  return f ? ((const float*)p)[i] : bf2f(((const ushort*)p)[i]);
}
DI f32x16 mfma_bf16(bf16x8 a, bf16x8 b, f32x16 c) {
  return __builtin_amdgcn_mfma_f32_32x32x16_bf16(a, b, c, 0, 0, 0);
}

// ---------------- dtype sniff ----------------
__global__ void k_sniff(const void* __restrict__ x, int* __restrict__ flag) {
  if (threadIdx.x == 0 && blockIdx.x == 0) {
    const ushort* u = (const ushort*)x;
    int garbage = 0, zeros = 0;
    for (int i = 0; i < 256; ++i) {
      float v = bf2f(u[i]);
      if (!(fabsf(v) < 1e9f)) garbage++;
      if ((i & 1) == 0 && u[i] == 0) zeros++;
    }
    flag[0] = (garbage >= 8 || zeros >= 100) ? 1 : 0;   // 1 = f32 buffers
  }
}

// ---------------- weight prep ----------------
// wAllf rows: [0,16) w_theta, [16,32) w_phi, [32,96) w_g   (f32, row*128+c)
// bAllf: [0,16) bT, [16,32) bP, [32,96) bG, [96,224) bAG
// wF: epilogue A-frags of w_attn_g: [ot4][ks4][lane64] -> 8 bf16
__global__ __launch_bounds__(256) void k_prep(
    const void* __restrict__ wT, const void* __restrict__ bT,
    const void* __restrict__ wP, const void* __restrict__ bP,
    const void* __restrict__ wG, const void* __restrict__ bG,
    const void* __restrict__ wAG, const void* __restrict__ bAG,
    const int* __restrict__ flag,
    float* __restrict__ wAllf, float* __restrict__ bAllf, uint4* __restrict__ wF)
{
  int t = threadIdx.x;
  int f = flag[0];
  if (blockIdx.x == 0) {
    for (int i = t; i < 16 * 128; i += 256) wAllf[i]        = ldany(wT, i, f);
    for (int i = t; i < 16 * 128; i += 256) wAllf[2048 + i] = ldany(wP, i, f);
    for (int i = t; i < 64 * 128; i += 256) wAllf[4096 + i] = ldany(wG, i, f);
    if (t < 16)  bAllf[t]       = ldany(bT, t, f);
    if (t < 16)  bAllf[16 + t]  = ldany(bP, t, f);
    if (t < 64)  bAllf[32 + t]  = ldany(bG, t, f);
    if (t < 128) bAllf[96 + t]  = ldany(bAG, t, f);
  } else {
    int idx = (blockIdx.x - 1) * 256 + t;  // 0..1023
    int lane = idx & 63, ks = (idx >> 6) & 3, ot = idx >> 8;
    size_t src = (size_t)(ot * 32 + (lane & 31)) * 64 + ks * 16 + (lane >> 5) * 8;
    union { uint4 v4; ushort s[8]; } o;
    #pragma unroll
    for (int j = 0; j < 8; ++j) o.s[j] = f2bf(ldany(wAG, src + j, f));
    wF[idx] = o.v4;
  }
}

// ---------------- projections ----------------
// 12 channel-groups of 8 outputs; each thread handles 2 q (an h-pair).
// grp 0-1: theta (tanh, scaled by log2e, bf16 [q][16])
// grp 2-3: phi   (maxpool pre-act, tanh, bf16 [m][16])
// grp 4-11: g    (maxpool, bf16 TRANSPOSED g_t[c][m] for direct PV B-frag loads)
__global__ __launch_bounds__(256) void k_proj(
    const void* __restrict__ x, const int* __restrict__ flag,
    const float* __restrict__ wAllf, const float* __restrict__ bAllf,
    ushort* __restrict__ theta, ushort* __restrict__ phi, ushort* __restrict__ g_t)
{
  int b = blockIdx.y;
  int grp = blockIdx.x >> 5, qt = blockIdx.x & 31;
  int t = threadIdx.x, lane = t & 63, wv = t >> 6;
  int q = qt * 512 + wv * 128 + lane * 2;
  int f = flag[0];
  const float* wp = wAllf + (grp << 10);

  float a0[8], a1[8];
  #pragma unroll
  for (int o = 0; o < 8; ++o) { a0[o] = 0.f; a1[o] = 0.f; }

  size_t xoff = (size_t)b * CH * NQ + q;
  if (f) {
    const float* xf = (const float*)x + xoff;
    for (int c0 = 0; c0 < CH; c0 += 8) {
      float2 xv[8];
      #pragma unroll
      for (int k = 0; k < 8; ++k) xv[k] = *(const float2*)(xf + (size_t)(c0 + k) * NQ);
      #pragma unroll
      for (int o = 0; o < 8; ++o) {
        #pragma unroll
        for (int k = 0; k < 8; ++k) {
          float wgt = wp[o * 128 + c0 + k];
          a0[o] = fmaf(xv[k].x, wgt, a0[o]);
          a1[o] = fmaf(xv[k].y, wgt, a1[o]);
        }
      }
    }
  } else {
    const ushort* xu = (const ushort*)x + xoff;
    for (int c0 = 0; c0 < CH; c0 += 8) {
      float xl[8], xh[8];
      #pragma unroll
      for (int k = 0; k < 8; ++k) {
        uint v = *(const uint*)(xu + (size_t)(c0 + k) * NQ);
        xl[k] = bf2f((ushort)(v & 0xFFFFu));
        xh[k] = bf2f((ushort)(v >> 16));
      }
      #pragma unroll
      for (int o = 0; o < 8; ++o) {
        #pragma unroll
        for (int k = 0; k < 8; ++k) {
          float wgt = wp[o * 128 + c0 + k];
          a0[o] = fmaf(xl[k], wgt, a0[o]);
          a1[o] = fmaf(xh[k], wgt, a1[o]);
        }
      }
    }
  }

  int bb = grp * 8;
  constexpr float L2E = 1.4426950408889634f;

  if (grp < 2) {
    union { uint4 v4; ushort s[8]; } t0, t1;
    #pragma unroll
    for (int o = 0; o < 8; ++o) {
      t0.s[o] = f2bf(tanhf(a0[o] + bAllf[bb + o]) * L2E);
      t1.s[o] = f2bf(tanhf(a1[o] + bAllf[bb + o]) * L2E);
    }
    *(uint4*)(theta + ((size_t)b * NQ + q) * 16 + bb)     = t0.v4;
    *(uint4*)(theta + ((size_t)b * NQ + q + 1) * 16 + bb) = t1.v4;
  } else {
    float z[8];
    #pragma unroll
    for (int o = 0; o < 8; ++o) {
      float m2 = fmaxf(a0[o], a1[o]) + bAllf[bb + o];   // h-pair in-thread
      z[o] = fmaxf(m2, __shfl_xor(m2, 16, 64));          // w-pair across lanes
    }
    if ((lane & 16) == 0) {
      int hh = q & 31, ww = (q >> 5) & 31, nn = q >> 10;
      int m = nn * 256 + (ww >> 1) * 16 + (hh >> 1);
      if (grp < 4) {
        union { uint4 v4; ushort s[8]; } ph;
        #pragma unroll
        for (int o = 0; o < 8; ++o) ph.s[o] = f2bf(tanhf(z[o]));
        *(uint4*)(phi + ((size_t)b * NM + m) * 16 + (bb - 16)) = ph.v4;
      } else {
        int c0 = bb - 32;
        #pragma unroll
        for (int o = 0; o < 8; ++o)
          g_t[((size_t)b * 64 + c0 + o) * NM + m] = f2bf(z[o]);
      }
    }
  }
}

// ---------------- softmax denominator partials ----------------
__global__ __launch_bounds__(256) void k_denom(
    const ushort* __restrict__ theta, const ushort* __restrict__ phi,
    float* __restrict__ partial)
{
  int b = blockIdx.z, qs = blockIdx.y;
  int w = threadIdx.x >> 6;
  int l = threadIdx.x & 63, lr = l & 31, lh = l >> 5;
  int m0 = blockIdx.x * 128 + w * 32;

  bf16x8 pB = __builtin_bit_cast(bf16x8, *(const uint4*)(phi + ((size_t)b * NM + m0 + lr) * 16 + lh * 8));

  float s = 0.f;
  int qb = qs * 1024;
  for (int qq = 0; qq < 1024; qq += 32) {
    bf16x8 tA = __builtin_bit_cast(bf16x8, *(const uint4*)(theta + ((size_t)b * NQ + qb + qq + lr) * 16 + lh * 8));
    f32x16 S;
    #pragma unroll
    for (int i = 0; i < 16; ++i) S[i] = 0.f;
    S = mfma_bf16(tA, pB, S);
    #pragma unroll
    for (int r = 0; r < 16; ++r) s += exp2f(S[r]);
  }
  s += __shfl_xor(s, 32, 64);
  if (l < 32) partial[(((size_t)b * 16 + qs) << 12) + m0 + lr] = s;
}

// ---------------- denominator reduce -> ld[m] = -log2(denom) ----------------
__global__ __launch_bounds__(256) void k_ld(
    const float* __restrict__ partial, float* __restrict__ ld)
{
  int idx = blockIdx.x * 256 + threadIdx.x;   // 8192
  int b = idx >> 12, m = idx & 4095;
  float s = 0.f;
  #pragma unroll
  for (int p = 0; p < 16; ++p) s += partial[(((size_t)b * 16 + p) << 12) + m];
  ld[idx] = -log2f(s);
}

// ---------------- fused attention + output ----------------
// Block: 64 q, 8 waves = (m-quarter mq) x (q-half qh). Swapped QK^T:
// S^T[m][q] = mfma(phi, theta, C=ld[m]) so softmax scale folds into the
// accumulator init and P's PV A-frags assemble IN-REGISTER via
// v_cvt_pk_bf16_f32 + v_permlane32_swap_b32 (no LDS round-trip).
__global__ __launch_bounds__(512) void k_attn(
    const ushort* __restrict__ theta, const ushort* __restrict__ phi,
    const ushort* __restrict__ g_t, const float* __restrict__ ld,
    const uint4* __restrict__ wF, const float* __restrict__ bAllf,
    const void* __restrict__ x, const void* __restrict__ gamma,
    const int* __restrict__ flag, void* __restrict__ out_base)
{
  int b = blockIdx.y;
  int q0 = blockIdx.x * 64;
  int t = threadIdx.x;
  int w = t >> 6, l = t & 63, lr = l & 31, lh = l >> 5;
  int mq = w & 3, qh = w >> 2;

  __shared__ float agPart[4][32][65];
  __shared__ __align__(16) ushort agF[32][80];

  int qw = q0 + qh * 32;
  // theta frag: B[k][col=q] (lane -> col=l&31, k=8*lh+j)
  bf16x8 tB = __builtin_bit_cast(bf16x8, *(const uint4*)(theta + ((size_t)b * NQ + qw + lr) * 16 + lh * 8));

  const ushort* gt0 = g_t + ((size_t)b * 64 + lr) * NM;
  const ushort* gt1 = gt0 + (size_t)32 * NM;
  const float* ldp = ld + (size_t)b * NM;

  f32x16 acc0, acc1;
  #pragma unroll
  for (int i = 0; i < 16; ++i) { acc0[i] = 0.f; acc1[i] = 0.f; }

  for (int it = 0; it < 32; ++it) {
    int m0 = mq * 32 + it * 128;
    // phi frag: A[row=m][k] (lane -> row=l&31, k=8*lh+j)
    bf16x8 pA = __builtin_bit_cast(bf16x8, *(const uint4*)(phi + ((size_t)b * NM + m0 + lr) * 16 + lh * 8));

    // accumulator init = ld[m] (row map: m = m0 + (r&3) + 8*(r>>2) + 4*lh)
    const float* lp = ldp + m0 + 4 * lh;
    float4 l0 = *(const float4*)(lp);
    float4 l1 = *(const float4*)(lp + 8);
    float4 l2 = *(const float4*)(lp + 16);
    float4 l3 = *(const float4*)(lp + 24);
    f32x16 S;
    S[0] = l0.x;  S[1] = l0.y;  S[2] = l0.z;  S[3] = l0.w;
    S[4] = l1.x;  S[5] = l1.y;  S[6] = l1.z;  S[7] = l1.w;
    S[8] = l2.x;  S[9] = l2.y;  S[10] = l2.z; S[11] = l2.w;
    S[12] = l3.x; S[13] = l3.y; S[14] = l3.z; S[15] = l3.w;

    S = mfma_bf16(pA, tB, S);   // S^T[m][q] + ld[m]

    uint4 g00 = *(const uint4*)(gt0 + m0 + lh * 8);
    uint4 g01 = *(const uint4*)(gt1 + m0 + lh * 8);
    uint4 g10 = *(const uint4*)(gt0 + m0 + 16 + lh * 8);
    uint4 g11 = *(const uint4*)(gt1 + m0 + 16 + lh * 8);

    #pragma unroll
    for (int r = 0; r < 16; ++r) S[r] = exp2f(S[r]);   // P[m][q], P<=1

    // pack pairs along m: w_i = {bf16(p_{2i}), bf16(p_{2i+1})}
    uint u0, u1, u2, u3, u4, u5, u6, u7;
    asm("v_cvt_pk_bf16_f32 %0, %1, %2" : "=v"(u0) : "v"(S[0]),  "v"(S[1]));
    asm("v_cvt_pk_bf16_f32 %0, %1, %2" : "=v"(u1) : "v"(S[2]),  "v"(S[3]));
    asm("v_cvt_pk_bf16_f32 %0, %1, %2" : "=v"(u2) : "v"(S[4]),  "v"(S[5]));
    asm("v_cvt_pk_bf16_f32 %0, %1, %2" : "=v"(u3) : "v"(S[6]),  "v"(S[7]));
    asm("v_cvt_pk_bf16_f32 %0, %1, %2" : "=v"(u4) : "v"(S[8]),  "v"(S[9]));
    asm("v_cvt_pk_bf16_f32 %0, %1, %2" : "=v"(u5) : "v"(S[10]), "v"(S[11]));
    asm("v_cvt_pk_bf16_f32 %0, %1, %2" : "=v"(u6) : "v"(S[12]), "v"(S[13]));
    asm("v_cvt_pk_bf16_f32 %0, %1, %2" : "=v"(u7) : "v"(S[14]), "v"(S[15]));

    // cross-half exchange: lane l and l+32 share q, hold complementary m's.
    asm("v_permlane32_swap_b32 %0, %1" : "+v"(u0), "+v"(u2));
    asm("v_permlane32_swap_b32 %0, %1" : "+v"(u1), "+v"(u3));
    asm("v_permlane32_swap_b32 %0, %1" : "+v"(u4), "+v"(u6));
    asm("v_permlane32_swap_b32 %0, %1" : "+v"(u5), "+v"(u7));

    uint4 fa0 = make_uint4(u0, u1, u2, u3);   // A[q][m_local 0..15]
    uint4 fa1 = make_uint4(u4, u5, u6, u7);   // A[q][m_local 16..31]

    acc0 = mfma_bf16(__builtin_bit_cast(bf16x8, fa0), __builtin_bit_cast(bf16x8, g00), acc0);
    acc1 = mfma_bf16(__builtin_bit_cast(bf16x8, fa0), __builtin_bit_cast(bf16x8, g01), acc1);
    acc0 = mfma_bf16(__builtin_bit_cast(bf16x8, fa1), __builtin_bit_cast(bf16x8, g10), acc0);
    acc1 = mfma_bf16(__builtin_bit_cast(bf16x8, fa1), __builtin_bit_cast(bf16x8, g11), acc1);
  }

  int mode = flag[0];
  float ga = ldany(gamma, 0, mode);
  float alpha = 1.f / (1.f + __expf(-ga));

  #pragma unroll
  for (int h = 0; h < 2; ++h) {
    __syncthreads();
    if (qh == h) {
      #pragma unroll
      for (int r = 0; r < 16; ++r) {
        int qq = (r & 3) + 8 * (r >> 2) + 4 * lh;
        agPart[mq][qq][lr]      = acc0[r];
        agPart[mq][qq][32 + lr] = acc1[r];
      }
    }
    __syncthreads();
    if (t < 256) {
      int w2 = t >> 6, l2 = t & 63, lr2 = l2 & 31, lh2 = l2 >> 5;
      #pragma unroll
      for (int jj = 0; jj < 8; ++jj) {
        int c = w2 * 16 + lh2 * 8 + jj;
        float vsum = agPart[0][lr2][c] + agPart[1][lr2][c] + agPart[2][lr2][c] + agPart[3][lr2][c];
        agF[lr2][c] = f2bf(vsum);
      }
    }
    __syncthreads();
    if (qh == h) {
      f32x16 oacc;
      #pragma unroll
      for (int i = 0; i < 16; ++i) oacc[i] = 0.f;
      #pragma unroll
      for (int ks = 0; ks < 4; ++ks) {
        bf16x8 aw = __builtin_bit_cast(bf16x8, wF[(mq * 4 + ks) * 64 + l]);
        bf16x8 bg = __builtin_bit_cast(bf16x8, *(const uint4*)&agF[lr][ks * 16 + lh * 8]);
        oacc = mfma_bf16(aw, bg, oacc);
      }
      if (mode) {
        float* o0 = (float*)out_base;
        float* o1 = o0 + NX;
        const float* xf = (const float*)x;
        #pragma unroll
        for (int r = 0; r < 16; ++r) {
          int o = mq * 32 + (r & 3) + 8 * (r >> 2) + 4 * lh;
          size_t oi = ((size_t)b * CH + o) * NQ + q0 + h * 32 + lr;
          float ag = oacc[r] + bAllf[96 + o];
          o0[oi] = (1.f - alpha) * xf[oi] + alpha * ag;
          o1[oi] = ag;
        }
      } else {
        ushort* o0 = (ushort*)out_base;
        ushort* o1 = o0 + NX;
        const ushort* xu = (const ushort*)x;
        #pragma unroll
        for (int r = 0; r < 16; ++r) {
          int o = mq * 32 + (r & 3) + 8 * (r >> 2) + 4 * lh;
          size_t oi = ((size_t)b * CH + o) * NQ + q0 + h * 32 + lr;
          float ag = oacc[r] + bAllf[96 + o];
          o0[oi] = f2bf((1.f - alpha) * bf2f(xu[oi]) + alpha * ag);
          o1[oi] = f2bf(ag);
        }
      }
    }
  }
}

extern "C" void kernel_launch(void* const* d_in, const int* in_sizes, int n_in,
                              void* d_out, int out_size, void* d_ws, size_t ws_size,
                              hipStream_t stream) {
  const void* x    = d_in[0];
  const void* wT   = d_in[1];
  const void* bT   = d_in[2];
  const void* wP   = d_in[3];
  const void* bP   = d_in[4];
  const void* wG   = d_in[5];
  const void* bG   = d_in[6];
  const void* wAG  = d_in[7];
  const void* bAG  = d_in[8];
  const void* gmm  = d_in[9];

  char* ws = (char*)d_ws;
  ushort* theta  = (ushort*)(ws + 0);          // 1 MB
  ushort* phi    = (ushort*)(ws + 1048576);    // 256 KB
  ushort* g_t    = (ushort*)(ws + 1310720);    // 1 MB  [b][c][m] bf16
  float*  part   = (float*) (ws + 2359296);    // 512 KB
  float*  ld     = (float*) (ws + 2883584);    // 32 KB  -log2(denom)
  uint4*  wF     = (uint4*) (ws + 2916352);    // 16 KB
  float*  wAllf  = (float*) (ws + 2932736);    // 48 KB
  float*  bAllf  = (float*) (ws + 2981888);    // 1 KB
  int*    flag   = (int*)   (ws + 2983936);    // 4 B

  k_sniff<<<dim3(1), dim3(64), 0, stream>>>(x, flag);
  k_prep<<<dim3(5), dim3(256), 0, stream>>>(wT, bT, wP, bP, wG, bG, wAG, bAG, flag, wAllf, bAllf, wF);
  k_proj<<<dim3(384, 2), dim3(256), 0, stream>>>(x, flag, wAllf, bAllf, theta, phi, g_t);
  k_denom<<<dim3(32, 16, 2), dim3(256), 0, stream>>>(theta, phi, part);
  k_ld<<<dim3(32), dim3(256), 0, stream>>>(part, ld);
  k_attn<<<dim3(256, 2), dim3(512), 0, stream>>>(theta, phi, g_t, ld, wF, bAllf, x, gmm, flag, d_out);
}